// Round 1
// 828.393 us; speedup vs baseline: 1.2597x; 1.2597x over previous
//
#include <hip/hip_runtime.h>
#include <hip/hip_bf16.h>
#include <math.h>

#define DM 768
#define NH 12
#define HD 64
#define B_ 4
#define SQ_ 1024
#define SK_ 2048
#define QT 16

typedef __bf16 bf16x8 __attribute__((ext_vector_type(8)));
typedef __bf16 bf16x4 __attribute__((ext_vector_type(4)));
typedef float f32x4 __attribute__((ext_vector_type(4)));

static __device__ __forceinline__ f32x4 mfma16(bf16x8 a, bf16x8 b, f32x4 c) {
    return __builtin_amdgcn_mfma_f32_16x16x32_bf16(a, b, c, 0, 0, 0);
}

// ---------------- block reductions (256 threads, 4 waves of 64) ----------------
__device__ __forceinline__ float blksum(float v, float* rb, int tid) {
#pragma unroll
    for (int off = 32; off; off >>= 1) v += __shfl_down(v, off, 64);
    if ((tid & 63) == 0) rb[tid >> 6] = v;
    __syncthreads();
    if (tid == 0) rb[4] = rb[0] + rb[1] + rb[2] + rb[3];
    __syncthreads();
    return rb[4];
}

// ---------------- W transpose + cast: Wt[n][k] bf16 from W[k][n] fp32 ----------
__global__ __launch_bounds__(256)
void transpose_cast(const float* __restrict__ W0, const float* __restrict__ W1,
                    const float* __restrict__ W2,
                    __hip_bfloat16* __restrict__ T0, __hip_bfloat16* __restrict__ T1,
                    __hip_bfloat16* __restrict__ T2)
{
    __shared__ float Ls[64][68];
    const int z = blockIdx.z;
    const float* W = (z == 0) ? W0 : (z == 1) ? W1 : W2;
    __hip_bfloat16* T = (z == 0) ? T0 : (z == 1) ? T1 : T2;
    const int k0 = blockIdx.y * 64, n0 = blockIdx.x * 64;
    const int tid = threadIdx.x;
    const int kl = tid >> 4, n4 = (tid & 15) * 4;
#pragma unroll
    for (int p = 0; p < 4; ++p) {
        float4 v = *(const float4*)&W[(size_t)(k0 + kl + p * 16) * DM + n0 + n4];
        *(float4*)&Ls[kl + p * 16][n4] = v;
    }
    __syncthreads();
    const int nl = tid >> 2, kq = (tid & 3) * 16;
    __hip_bfloat16 tmp[16];
#pragma unroll
    for (int i = 0; i < 16; ++i) tmp[i] = __float2bfloat16(Ls[kq + i][nl]);
    *(bf16x8*)&T[(size_t)(n0 + nl) * DM + k0 + kq]     = *(bf16x8*)&tmp[0];
    *(bf16x8*)&T[(size_t)(n0 + nl) * DM + k0 + kq + 8] = *(bf16x8*)&tmp[8];
}

// ---------------- split-bf16 MFMA GEMM: C[M x 768] = A[M x 768] @ W[768 x 768] --
// A fp32 split to hi+lo bf16 in LDS (2 MFMA terms); W pre-transposed bf16 Wt[n][k].
// 128x128 C-tile, BK=32, 256 threads (4 waves 2x2, each 64x64 via 4x4 16x16 frags).
// MODE 0: bf16 head-split outb[((b*NH+h)*S + s)*HD + hd]
// MODE 1: fp32 flat outf[r*DM+c] = acc + bias[c] + resid[r*DM+c]
// MODE 2: bf16 head-split TRANSPOSED outb[((b*NH+h)*HD + hd)*S + s]  (for Vt)
template <int MODE>
__global__ __launch_bounds__(256)
void gemm_mfma(const float* __restrict__ A, const __hip_bfloat16* __restrict__ Wt,
               float* __restrict__ outf, __hip_bfloat16* __restrict__ outb, int S,
               const float* __restrict__ bias, const float* __restrict__ resid)
{
    __shared__ __hip_bfloat16 Ah[128][48];   // stride 96 B: 16B-aligned, conflict-free
    __shared__ __hip_bfloat16 Al[128][48];
    __shared__ __hip_bfloat16 Ws[128][48];

    const int tid  = threadIdx.x;
    const int lane = tid & 63;
    const int w    = tid >> 6;
    const int l16  = lane & 15;
    const int lq   = lane >> 4;
    const int wr   = w >> 1, wc = w & 1;

    const int bn = blockIdx.x % (DM / 128);
    const int bm = blockIdx.x / (DM / 128);
    const int row0 = bm * 128, col0 = bn * 128;

    // staging maps: 2 threads per row, 16 elems each
    const int m_a = tid >> 1;
    const int ka  = (tid & 1) * 16;

    const float* aptr = A + (size_t)(row0 + m_a) * DM + ka;
    const __hip_bfloat16* wptr = Wt + (size_t)(col0 + m_a) * DM + ka;

    f32x4 acc[4][4] = {};

    float4 areg[4];
    bf16x8 wreg[2];
#pragma unroll
    for (int i = 0; i < 4; ++i) areg[i] = *(const float4*)(aptr + 4 * i);
#pragma unroll
    for (int u = 0; u < 2; ++u) wreg[u] = *(const bf16x8*)(wptr + 8 * u);

    for (int c = 0; c < DM / 32; ++c) {
        __syncthreads();
        // convert + store to LDS
#pragma unroll
        for (int i = 0; i < 4; ++i) {
            float xs[4] = {areg[i].x, areg[i].y, areg[i].z, areg[i].w};
            bf16x4 hi, lo;
#pragma unroll
            for (int e = 0; e < 4; ++e) {
                const float x  = xs[e];
                const __bf16 h = (__bf16)x;
                const float hf = (float)h;
                hi[e] = h;
                lo[e] = (__bf16)(x - hf);
            }
            *(bf16x4*)&Ah[m_a][ka + 4 * i] = hi;
            *(bf16x4*)&Al[m_a][ka + 4 * i] = lo;
        }
        *(bf16x8*)&Ws[m_a][ka]     = wreg[0];
        *(bf16x8*)&Ws[m_a][ka + 8] = wreg[1];
        __syncthreads();

        if (c + 1 < DM / 32) {   // issue next chunk's global loads under the MFMAs
            const float* ap = aptr + (size_t)(c + 1) * 32;
            const __hip_bfloat16* wp = wptr + (size_t)(c + 1) * 32;
#pragma unroll
            for (int i = 0; i < 4; ++i) areg[i] = *(const float4*)(ap + 4 * i);
#pragma unroll
            for (int u = 0; u < 2; ++u) wreg[u] = *(const bf16x8*)(wp + 8 * u);
        }

        bf16x8 bfr[4];
#pragma unroll
        for (int j = 0; j < 4; ++j)
            bfr[j] = *(const bf16x8*)&Ws[wc * 64 + j * 16 + l16][lq * 8];
#pragma unroll
        for (int i = 0; i < 4; ++i) {
            const bf16x8 ah = *(const bf16x8*)&Ah[wr * 64 + i * 16 + l16][lq * 8];
            const bf16x8 al = *(const bf16x8*)&Al[wr * 64 + i * 16 + l16][lq * 8];
#pragma unroll
            for (int j = 0; j < 4; ++j) {
                acc[i][j] = mfma16(ah, bfr[j], acc[i][j]);
                acc[i][j] = mfma16(al, bfr[j], acc[i][j]);
            }
        }
    }

    // ---- epilogue: C[row][col], row = row0+wr*64+i*16+lq*4+rr, col = col0+wc*64+j*16+l16
    int b_blk = 0, s_base = 0;
    if (MODE != 1) {
        b_blk  = row0 / S;
        s_base = row0 - b_blk * S + wr * 64;
    }
#pragma unroll
    for (int i = 0; i < 4; ++i) {
#pragma unroll
        for (int j = 0; j < 4; ++j) {
#pragma unroll
            for (int rr = 0; rr < 4; ++rr) {
                const int cc = col0 + wc * 64 + j * 16 + l16;
                if (MODE == 1) {
                    const int r = row0 + wr * 64 + i * 16 + lq * 4 + rr;
                    outf[(size_t)r * DM + cc] =
                        acc[i][j][rr] + bias[cc] + resid[(size_t)r * DM + cc];
                } else {
                    const int s  = s_base + i * 16 + lq * 4 + rr;
                    const int h  = cc >> 6, hd = cc & 63;
                    if (MODE == 0)
                        outb[(((size_t)b_blk * NH + h) * S + s) * HD + hd] =
                            __float2bfloat16(acc[i][j][rr]);
                    else
                        outb[(((size_t)b_blk * NH + h) * HD + hd) * S + s] =
                            __float2bfloat16(acc[i][j][rr]);
                }
            }
        }
    }
}

// ---------------- MFMA attention: 16 q-rows x full SK per block ----------------
// p (exp'd, masked scores) in exactly 64 KB LDS as bf16.
// Wave w: QK^T strip k in [512w,512w+512); PV d-tile [16w,16w+16).
__global__ __launch_bounds__(256)
void attn_mfma(const __hip_bfloat16* __restrict__ Qb,
               const __hip_bfloat16* __restrict__ Kb,
               const __hip_bfloat16* __restrict__ Vt,
               const int* __restrict__ mask, const float* __restrict__ temp,
               float* __restrict__ attn, float* __restrict__ ctx)
{
    __shared__ __hip_bfloat16 p_s[QT * SK_];   // 65536 B exactly

    const int tid  = threadIdx.x;
    const int lane = tid & 63;
    const int w    = tid >> 6;
    const int l16  = lane & 15;
    const int lq   = lane >> 4;

    const int nqt = SQ_ / QT;                  // 64
    const int qt  = blockIdx.x % nqt;
    const int h   = (blockIdx.x / nqt) % NH;
    const int b   = blockIdx.x / (nqt * NH);
    const int q0  = qt * QT;

    const float factor = 0.125f / temp[0];

    const __hip_bfloat16* Qbase = Qb + (((size_t)b * NH + h) * SQ_ + q0) * HD;
    const __hip_bfloat16* Kbase = Kb + ((size_t)b * NH + h) * SK_ * HD;
    const __hip_bfloat16* Vbase = Vt + ((size_t)b * NH + h) * HD * SK_;

    // Q fragments (A operand), two d-halves, held in registers
    bf16x8 a0 = *(const bf16x8*)&Qbase[(size_t)l16 * HD + lq * 8];
    bf16x8 a1 = *(const bf16x8*)&Qbase[(size_t)l16 * HD + 32 + lq * 8];

    // ---- QK^T + mask + exp fused (no max-sub: |scores| <~ 2, fp32-safe) ----
    for (int t = 0; t < 32; ++t) {
        const int k0 = w * 512 + t * 16;
        const __hip_bfloat16* Krow = &Kbase[(size_t)(k0 + l16) * HD];
        bf16x8 b0 = *(const bf16x8*)&Krow[lq * 8];
        bf16x8 b1 = *(const bf16x8*)&Krow[32 + lq * 8];
        f32x4 acc = {};
        acc = mfma16(a0, b0, acc);
        acc = mfma16(a1, b1, acc);
        const bool live = mask[b * SK_ + k0 + l16] != 0;
#pragma unroll
        for (int r = 0; r < 4; ++r) {
            const float e = live ? __expf(acc[r] * factor) : 0.f;
            p_s[(size_t)(lq * 4 + r) * SK_ + k0 + l16] = __float2bfloat16(e);
        }
    }
    __syncthreads();

    // ---- row sums (every wave computes all 16 rows -> stats stay in regs) ----
    float sinv[QT];
#pragma unroll
    for (int r = 0; r < QT; ++r) {
        float s = 0.f;
#pragma unroll
        for (int it = 0; it < 4; ++it) {
            bf16x8 v = *(const bf16x8*)&p_s[r * SK_ + it * 512 + lane * 8];
#pragma unroll
            for (int j = 0; j < 8; ++j) s += (float)v[j];
        }
#pragma unroll
        for (int off = 32; off; off >>= 1) s += __shfl_xor(s, off, 64);
        sinv[r] = 1.f / s;
    }

    // ---- normalized attn write: wave w owns rows 4w..4w+3 ----
#pragma unroll
    for (int i = 0; i < 4; ++i) {
        const int r = 4 * w + i;
        const float inv = (w == 0) ? sinv[i] : (w == 1) ? sinv[4 + i]
                        : (w == 2) ? sinv[8 + i] : sinv[12 + i];
        float* arow = attn + ((size_t)((b * NH + h) * SQ_) + q0 + r) * SK_;
#pragma unroll
        for (int it = 0; it < 4; ++it) {
            bf16x8 v = *(const bf16x8*)&p_s[r * SK_ + it * 512 + lane * 8];
            float4 o0, o1;
            o0.x = (float)v[0] * inv; o0.y = (float)v[1] * inv;
            o0.z = (float)v[2] * inv; o0.w = (float)v[3] * inv;
            o1.x = (float)v[4] * inv; o1.y = (float)v[5] * inv;
            o1.z = (float)v[6] * inv; o1.w = (float)v[7] * inv;
            *(float4*)&arow[it * 512 + lane * 8]     = o0;
            *(float4*)&arow[it * 512 + lane * 8 + 4] = o1;
        }
    }

    // ---- PV: wave w -> d-tile [16w, 16w+16), full 2048 k ----
    f32x4 accp = {};
    for (int kc = 0; kc < SK_ / 32; ++kc) {
        bf16x8 ap = *(const bf16x8*)&p_s[l16 * SK_ + kc * 32 + lq * 8];
        bf16x8 bp = *(const bf16x8*)&Vbase[(size_t)(w * 16 + l16) * SK_ + kc * 32 + lq * 8];
        accp = mfma16(ap, bp, accp);
    }
#pragma unroll
    for (int r = 0; r < 4; ++r) {
        const int row = lq * 4 + r;
        const float inv = (lq == 0) ? sinv[r] : (lq == 1) ? sinv[4 + r]
                        : (lq == 2) ? sinv[8 + r] : sinv[12 + r];
        ctx[((size_t)(b * SQ_) + q0 + row) * DM + h * HD + w * 16 + l16] = accp[r] * inv;
    }
}

// ---------------- in-place LayerNorm on d_out rows ----------------
__global__ __launch_bounds__(256)
void ln_kernel(float* __restrict__ x, const float* __restrict__ gamma,
               const float* __restrict__ beta)
{
    __shared__ float rb[8];
    const int row = blockIdx.x;
    const int tid = threadIdx.x;
    float v[3];
    float s = 0.f;
#pragma unroll
    for (int i = 0; i < 3; ++i) {
        v[i] = x[(size_t)row * DM + tid + i * 256];
        s += v[i];
    }
    s = blksum(s, rb, tid);
    const float mean = s * (1.0f / DM);
    float s2 = 0.f;
#pragma unroll
    for (int i = 0; i < 3; ++i) {
        const float d = v[i] - mean;
        s2 += d * d;
    }
    s2 = blksum(s2, rb, tid);
    const float rstd = rsqrtf(s2 * (1.0f / DM) + 1e-5f);
#pragma unroll
    for (int i = 0; i < 3; ++i) {
        const int c = tid + i * 256;
        x[(size_t)row * DM + c] = gamma[c] * (v[i] - mean) * rstd + beta[c];
    }
}

extern "C" void kernel_launch(void* const* d_in, const int* in_sizes, int n_in,
                              void* d_out, int out_size, void* d_ws, size_t ws_size,
                              hipStream_t stream)
{
    const float* query = (const float*)d_in[0];
    const float* key   = (const float*)d_in[1];
    const float* value = (const float*)d_in[2];
    const int*   mask  = (const int*)d_in[3];
    const float* Wq    = (const float*)d_in[4];
    const float* Wk    = (const float*)d_in[5];
    const float* Wv    = (const float*)d_in[6];
    const float* Wo    = (const float*)d_in[7];
    const float* bo    = (const float*)d_in[8];
    const float* gamma = (const float*)d_in[9];
    const float* beta  = (const float*)d_in[10];
    const float* temp  = (const float*)d_in[11];

    float* out  = (float*)d_out;                          // [B,SQ,DM]
    float* attn = out + (size_t)B_ * SQ_ * DM;            // [B,NH,SQ,SK] fp32

    __hip_bfloat16* Qb = (__hip_bfloat16*)d_ws;           // [B,NH,SQ,HD]
    __hip_bfloat16* Kb = Qb + (size_t)B_ * NH * SQ_ * HD; // [B,NH,SK,HD]
    __hip_bfloat16* Vt = Kb + (size_t)B_ * NH * SK_ * HD; // [B,NH,HD,SK]
    float* ctx = (float*)(Vt + (size_t)B_ * NH * SK_ * HD); // [B,SQ,DM] fp32

    // transient weight transposes, parked in regions not yet written:
    //   Wqt/Wkt/Wvt live in the ctx area (ctx is produced later by attn_mfma)
    //   Wot lives in the Qb area (Qb is dead after attn_mfma)
    __hip_bfloat16* Wqt = (__hip_bfloat16*)ctx;
    __hip_bfloat16* Wkt = Wqt + (size_t)DM * DM;
    __hip_bfloat16* Wvt = Wkt + (size_t)DM * DM;
    __hip_bfloat16* Wot = Qb;

    dim3 blk(256);
    hipLaunchKernelGGL(transpose_cast, dim3(12, 12, 3), blk, 0, stream,
                       Wq, Wk, Wv, Wqt, Wkt, Wvt);
    hipLaunchKernelGGL((gemm_mfma<0>), dim3((B_ * SQ_ / 128) * (DM / 128)), blk, 0, stream,
                       query, Wqt, (float*)nullptr, Qb, SQ_, (const float*)nullptr, (const float*)nullptr);
    hipLaunchKernelGGL((gemm_mfma<0>), dim3((B_ * SK_ / 128) * (DM / 128)), blk, 0, stream,
                       key, Wkt, (float*)nullptr, Kb, SK_, (const float*)nullptr, (const float*)nullptr);
    hipLaunchKernelGGL((gemm_mfma<2>), dim3((B_ * SK_ / 128) * (DM / 128)), blk, 0, stream,
                       value, Wvt, (float*)nullptr, Vt, SK_, (const float*)nullptr, (const float*)nullptr);
    hipLaunchKernelGGL(attn_mfma, dim3(B_ * NH * (SQ_ / QT)), blk, 0, stream,
                       Qb, Kb, Vt, mask, temp, attn, ctx);
    hipLaunchKernelGGL(transpose_cast, dim3(12, 12, 1), blk, 0, stream,
                       Wo, Wo, Wo, Wot, Wot, Wot);
    hipLaunchKernelGGL((gemm_mfma<1>), dim3((B_ * SQ_ / 128) * (DM / 128)), blk, 0, stream,
                       ctx, Wot, out, (__hip_bfloat16*)nullptr, SQ_, bo, query);
    hipLaunchKernelGGL(ln_kernel, dim3(B_ * SQ_), blk, 0, stream, out, gamma, beta);
}

// Round 4
// 821.683 us; speedup vs baseline: 1.2699x; 1.0082x over previous
//
#include <hip/hip_runtime.h>
#include <hip/hip_bf16.h>
#include <math.h>

#define DM 768
#define NH 12
#define HD 64
#define B_ 4
#define SQ_ 1024
#define SK_ 2048
#define QT 16

typedef __bf16 bf16x8 __attribute__((ext_vector_type(8)));
typedef __bf16 bf16x4 __attribute__((ext_vector_type(4)));
typedef float f32x4 __attribute__((ext_vector_type(4)));

static __device__ __forceinline__ f32x4 mfma16(bf16x8 a, bf16x8 b, f32x4 c) {
    return __builtin_amdgcn_mfma_f32_16x16x32_bf16(a, b, c, 0, 0, 0);
}

// ---------------- block reductions (256 threads, 4 waves of 64) ----------------
__device__ __forceinline__ float blksum(float v, float* rb, int tid) {
#pragma unroll
    for (int off = 32; off; off >>= 1) v += __shfl_down(v, off, 64);
    if ((tid & 63) == 0) rb[tid >> 6] = v;
    __syncthreads();
    if (tid == 0) rb[4] = rb[0] + rb[1] + rb[2] + rb[3];
    __syncthreads();
    return rb[4];
}

// ---------------- W transpose + cast: Wt[n][k] bf16 from W[k][n] fp32 ----------
__global__ __launch_bounds__(256)
void transpose_cast(const float* __restrict__ W0, const float* __restrict__ W1,
                    const float* __restrict__ W2,
                    __hip_bfloat16* __restrict__ T0, __hip_bfloat16* __restrict__ T1,
                    __hip_bfloat16* __restrict__ T2)
{
    __shared__ float Ls[64][68];
    const int z = blockIdx.z;
    const float* W = (z == 0) ? W0 : (z == 1) ? W1 : W2;
    __hip_bfloat16* T = (z == 0) ? T0 : (z == 1) ? T1 : T2;
    const int k0 = blockIdx.y * 64, n0 = blockIdx.x * 64;
    const int tid = threadIdx.x;
    const int kl = tid >> 4, n4 = (tid & 15) * 4;
#pragma unroll
    for (int p = 0; p < 4; ++p) {
        float4 v = *(const float4*)&W[(size_t)(k0 + kl + p * 16) * DM + n0 + n4];
        *(float4*)&Ls[kl + p * 16][n4] = v;
    }
    __syncthreads();
    const int nl = tid >> 2, kq = (tid & 3) * 16;
    __hip_bfloat16 tmp[16];
#pragma unroll
    for (int i = 0; i < 16; ++i) tmp[i] = __float2bfloat16(Ls[kq + i][nl]);
    *(bf16x8*)&T[(size_t)(n0 + nl) * DM + k0 + kq]     = *(bf16x8*)&tmp[0];
    *(bf16x8*)&T[(size_t)(n0 + nl) * DM + k0 + kq + 8] = *(bf16x8*)&tmp[8];
}

// ---------------- split-bf16 MFMA GEMM: C[M x 768] = A[M x 768] @ W[768 x 768] --
// A fp32 split to hi+lo bf16 in LDS (2 MFMA terms); W pre-transposed bf16 Wt[n][k].
// 128x128 C-tile, BK=32, 256 threads (4 waves 2x2, each 64x64 via 4x4 16x16 frags).
// LDS stride 40 bf16 (80 B = 20 dwords): 16 frag rows span all 32 banks, 2/bank.
// MODE 0: bf16 head-split outb[((b*NH+h)*S + s)*HD + hd]
// MODE 1: fp32 flat outf[r*DM+c] = acc + bias[c] + resid[r*DM+c]
// MODE 2: bf16 head-split TRANSPOSED outb[((b*NH+h)*HD + hd)*S + s]  (for Vt)
template <int MODE>
__global__ __launch_bounds__(256)
void gemm_mfma(const float* __restrict__ A, const __hip_bfloat16* __restrict__ Wt,
               float* __restrict__ outf, __hip_bfloat16* __restrict__ outb, int S,
               const float* __restrict__ bias, const float* __restrict__ resid)
{
    __shared__ __hip_bfloat16 Ah[128][40];
    __shared__ __hip_bfloat16 Al[128][40];
    __shared__ __hip_bfloat16 Ws[128][40];

    const int tid  = threadIdx.x;
    const int lane = tid & 63;
    const int w    = tid >> 6;
    const int l16  = lane & 15;
    const int lq   = lane >> 4;
    const int wr   = w >> 1, wc = w & 1;

    const int bn = blockIdx.x % (DM / 128);
    const int bm = blockIdx.x / (DM / 128);
    const int row0 = bm * 128, col0 = bn * 128;

    // staging maps: 2 threads per row, 16 elems each
    const int m_a = tid >> 1;
    const int ka  = (tid & 1) * 16;

    const float* aptr = A + (size_t)(row0 + m_a) * DM + ka;
    const __hip_bfloat16* wptr = Wt + (size_t)(col0 + m_a) * DM + ka;

    f32x4 acc[4][4] = {};

    float4 areg[4];
    bf16x8 wreg[2];
#pragma unroll
    for (int i = 0; i < 4; ++i) areg[i] = *(const float4*)(aptr + 4 * i);
#pragma unroll
    for (int u = 0; u < 2; ++u) wreg[u] = *(const bf16x8*)(wptr + 8 * u);

    for (int c = 0; c < DM / 32; ++c) {
        __syncthreads();
        // convert + store to LDS
#pragma unroll
        for (int i = 0; i < 4; ++i) {
            float xs[4] = {areg[i].x, areg[i].y, areg[i].z, areg[i].w};
            bf16x4 hi, lo;
#pragma unroll
            for (int e = 0; e < 4; ++e) {
                const float x  = xs[e];
                const __bf16 h = (__bf16)x;
                const float hf = (float)h;
                hi[e] = h;
                lo[e] = (__bf16)(x - hf);
            }
            *(bf16x4*)&Ah[m_a][ka + 4 * i] = hi;
            *(bf16x4*)&Al[m_a][ka + 4 * i] = lo;
        }
        *(bf16x8*)&Ws[m_a][ka]     = wreg[0];
        *(bf16x8*)&Ws[m_a][ka + 8] = wreg[1];
        __syncthreads();

        if (c + 1 < DM / 32) {   // issue next chunk's global loads under the MFMAs
            const float* ap = aptr + (size_t)(c + 1) * 32;
            const __hip_bfloat16* wp = wptr + (size_t)(c + 1) * 32;
#pragma unroll
            for (int i = 0; i < 4; ++i) areg[i] = *(const float4*)(ap + 4 * i);
#pragma unroll
            for (int u = 0; u < 2; ++u) wreg[u] = *(const bf16x8*)(wp + 8 * u);
        }

        bf16x8 bfr[4];
#pragma unroll
        for (int j = 0; j < 4; ++j)
            bfr[j] = *(const bf16x8*)&Ws[wc * 64 + j * 16 + l16][lq * 8];
#pragma unroll
        for (int i = 0; i < 4; ++i) {
            const bf16x8 ah = *(const bf16x8*)&Ah[wr * 64 + i * 16 + l16][lq * 8];
            const bf16x8 al = *(const bf16x8*)&Al[wr * 64 + i * 16 + l16][lq * 8];
#pragma unroll
            for (int j = 0; j < 4; ++j) {
                acc[i][j] = mfma16(ah, bfr[j], acc[i][j]);
                acc[i][j] = mfma16(al, bfr[j], acc[i][j]);
            }
        }
    }

    // ---- epilogue: C[row][col], row = row0+wr*64+i*16+lq*4+rr, col = col0+wc*64+j*16+l16
    int b_blk = 0, s_base = 0;
    if (MODE != 1) {
        b_blk  = row0 / S;
        s_base = row0 - b_blk * S + wr * 64;
    }
#pragma unroll
    for (int i = 0; i < 4; ++i) {
#pragma unroll
        for (int j = 0; j < 4; ++j) {
#pragma unroll
            for (int rr = 0; rr < 4; ++rr) {
                const int cc = col0 + wc * 64 + j * 16 + l16;
                if (MODE == 1) {
                    const int r = row0 + wr * 64 + i * 16 + lq * 4 + rr;
                    outf[(size_t)r * DM + cc] =
                        acc[i][j][rr] + bias[cc] + resid[(size_t)r * DM + cc];
                } else {
                    const int s  = s_base + i * 16 + lq * 4 + rr;
                    const int h  = cc >> 6, hd = cc & 63;
                    if (MODE == 0)
                        outb[(((size_t)b_blk * NH + h) * S + s) * HD + hd] =
                            __float2bfloat16(acc[i][j][rr]);
                    else
                        outb[(((size_t)b_blk * NH + h) * HD + hd) * S + s] =
                            __float2bfloat16(acc[i][j][rr]);
                }
            }
        }
    }
}

// ---------------- MFMA attention: 16 q-rows x full SK per block ----------------
// p (exp'd, masked scores) in exactly 64 KB LDS as bf16, XOR-swizzled on 16 B
// granules: phys_granule = g ^ f(row), f(row) = (row + 3*(row>>3)) & 7.
// Makes QK writes (4 rows), attn-write reads (1 row/64 granules) and PV reads
// (16 rows, same granule column) all <=2 lanes/bank.
// Wave w: QK^T strip k in [512w,512w+512); attn rows 4w..4w+3; PV d-tile [16w,16w+16).
__global__ __launch_bounds__(256)
void attn_mfma(const __hip_bfloat16* __restrict__ Qb,
               const __hip_bfloat16* __restrict__ Kb,
               const __hip_bfloat16* __restrict__ Vt,
               const int* __restrict__ mask, const float* __restrict__ temp,
               float* __restrict__ attn, float* __restrict__ ctx)
{
    __shared__ __hip_bfloat16 p_s[QT * SK_];   // 65536 B exactly

    const int tid  = threadIdx.x;
    const int lane = tid & 63;
    const int w    = tid >> 6;
    const int l16  = lane & 15;
    const int lq   = lane >> 4;

    const int nqt = SQ_ / QT;                  // 64
    const int qt  = blockIdx.x % nqt;
    const int h   = (blockIdx.x / nqt) % NH;
    const int b   = blockIdx.x / (nqt * NH);
    const int q0  = qt * QT;

    const float factor = 0.125f / temp[0];

    const __hip_bfloat16* Qbase = Qb + (((size_t)b * NH + h) * SQ_ + q0) * HD;
    const __hip_bfloat16* Kbase = Kb + ((size_t)b * NH + h) * SK_ * HD;
    const __hip_bfloat16* Vbase = Vt + ((size_t)b * NH + h) * HD * SK_;

    // Q fragments (A operand), two d-halves, held in registers
    bf16x8 a0 = *(const bf16x8*)&Qbase[(size_t)l16 * HD + lq * 8];
    bf16x8 a1 = *(const bf16x8*)&Qbase[(size_t)l16 * HD + 32 + lq * 8];

    // swizzle constants for the 4 rows this lane's lq-group writes in QK phase
    int frow[4];
#pragma unroll
    for (int r = 0; r < 4; ++r) {
        const int row = lq * 4 + r;
        frow[r] = (row + 3 * (row >> 3)) & 7;
    }
    const int ebase = l16 & 7;

    // ---- QK^T + mask + exp fused (no max-sub: |scores| <~ 2, fp32-safe) ----
    for (int t = 0; t < 32; ++t) {
        const int k0 = w * 512 + t * 16;
        const __hip_bfloat16* Krow = &Kbase[(size_t)(k0 + l16) * HD];
        bf16x8 b0 = *(const bf16x8*)&Krow[lq * 8];
        bf16x8 b1 = *(const bf16x8*)&Krow[32 + lq * 8];
        f32x4 acc = {};
        acc = mfma16(a0, b0, acc);
        acc = mfma16(a1, b1, acc);
        const bool live = mask[b * SK_ + k0 + l16] != 0;
        const int g = w * 64 + t * 2 + (l16 >> 3);     // logical 16B-granule
#pragma unroll
        for (int r = 0; r < 4; ++r) {
            const int row = lq * 4 + r;
            const float e = live ? __expf(acc[r] * factor) : 0.f;
            p_s[row * SK_ + ((g ^ frow[r]) << 3) + ebase] = __float2bfloat16(e);
        }
    }
    __syncthreads();

    // ---- wave w owns rows 4w..4w+3: single LDS pass -> sum + normalize + write ----
    float inv4[4];
#pragma unroll
    for (int i = 0; i < 4; ++i) {
        const int r = 4 * w + i;
        const int fr = (r + 3 * (r >> 3)) & 7;
        bf16x8 vv[4];
        float s = 0.f;
#pragma unroll
        for (int it = 0; it < 4; ++it) {
            const int g = it * 64 + lane;
            vv[it] = *(const bf16x8*)&p_s[r * SK_ + ((g ^ fr) << 3)];
#pragma unroll
            for (int j = 0; j < 8; ++j) s += (float)vv[it][j];
        }
#pragma unroll
        for (int off = 32; off; off >>= 1) s += __shfl_xor(s, off, 64);
        const float inv = 1.f / s;
        inv4[i] = inv;
        float* arow = attn + ((size_t)((b * NH + h) * SQ_) + q0 + r) * SK_;
#pragma unroll
        for (int it = 0; it < 4; ++it) {
            const int g = it * 64 + lane;              // logical col = g*8
            float4 o0, o1;
            o0.x = (float)vv[it][0] * inv; o0.y = (float)vv[it][1] * inv;
            o0.z = (float)vv[it][2] * inv; o0.w = (float)vv[it][3] * inv;
            o1.x = (float)vv[it][4] * inv; o1.y = (float)vv[it][5] * inv;
            o1.z = (float)vv[it][6] * inv; o1.w = (float)vv[it][7] * inv;
            *(float4*)&arow[(size_t)g * 8]     = o0;
            *(float4*)&arow[(size_t)g * 8 + 4] = o1;
        }
    }

    // ---- PV: wave w -> d-tile [16w, 16w+16), full 2048 k (unnormalized) ----
    f32x4 accp = {};
    const int fl = (l16 + 3 * (l16 >> 3)) & 7;
    for (int kc = 0; kc < SK_ / 32; ++kc) {
        const int g = kc * 4 + lq;
        bf16x8 ap = *(const bf16x8*)&p_s[l16 * SK_ + ((g ^ fl) << 3)];
        bf16x8 bp = *(const bf16x8*)&Vbase[(size_t)(w * 16 + l16) * SK_ + kc * 32 + lq * 8];
        accp = mfma16(ap, bp, accp);
    }

    // ---- p_s dead: stash the 16 inv-sums in its first 64 B, then normalize ctx ----
    __syncthreads();
    float* fb = (float*)p_s;
    if (lane == 0) {
        fb[w * 4 + 0] = inv4[0];
        fb[w * 4 + 1] = inv4[1];
        fb[w * 4 + 2] = inv4[2];
        fb[w * 4 + 3] = inv4[3];
    }
    __syncthreads();
#pragma unroll
    for (int r = 0; r < 4; ++r) {
        const int row = lq * 4 + r;
        const float inv = fb[row];
        ctx[((size_t)(b * SQ_) + q0 + row) * DM + h * HD + w * 16 + l16] = accp[r] * inv;
    }
}

// ---------------- in-place LayerNorm on d_out rows ----------------
__global__ __launch_bounds__(256)
void ln_kernel(float* __restrict__ x, const float* __restrict__ gamma,
               const float* __restrict__ beta)
{
    __shared__ float rb[8];
    const int row = blockIdx.x;
    const int tid = threadIdx.x;
    float v[3];
    float s = 0.f;
#pragma unroll
    for (int i = 0; i < 3; ++i) {
        v[i] = x[(size_t)row * DM + tid + i * 256];
        s += v[i];
    }
    s = blksum(s, rb, tid);
    const float mean = s * (1.0f / DM);
    float s2 = 0.f;
#pragma unroll
    for (int i = 0; i < 3; ++i) {
        const float d = v[i] - mean;
        s2 += d * d;
    }
    s2 = blksum(s2, rb, tid);
    const float rstd = rsqrtf(s2 * (1.0f / DM) + 1e-5f);
#pragma unroll
    for (int i = 0; i < 3; ++i) {
        const int c = tid + i * 256;
        x[(size_t)row * DM + c] = gamma[c] * (v[i] - mean) * rstd + beta[c];
    }
}

extern "C" void kernel_launch(void* const* d_in, const int* in_sizes, int n_in,
                              void* d_out, int out_size, void* d_ws, size_t ws_size,
                              hipStream_t stream)
{
    const float* query = (const float*)d_in[0];
    const float* key   = (const float*)d_in[1];
    const float* value = (const float*)d_in[2];
    const int*   mask  = (const int*)d_in[3];
    const float* Wq    = (const float*)d_in[4];
    const float* Wk    = (const float*)d_in[5];
    const float* Wv    = (const float*)d_in[6];
    const float* Wo    = (const float*)d_in[7];
    const float* bo    = (const float*)d_in[8];
    const float* gamma = (const float*)d_in[9];
    const float* beta  = (const float*)d_in[10];
    const float* temp  = (const float*)d_in[11];

    float* out  = (float*)d_out;                          // [B,SQ,DM]
    float* attn = out + (size_t)B_ * SQ_ * DM;            // [B,NH,SQ,SK] fp32

    __hip_bfloat16* Qb = (__hip_bfloat16*)d_ws;           // [B,NH,SQ,HD]
    __hip_bfloat16* Kb = Qb + (size_t)B_ * NH * SQ_ * HD; // [B,NH,SK,HD]
    __hip_bfloat16* Vt = Kb + (size_t)B_ * NH * SK_ * HD; // [B,NH,HD,SK]
    float* ctx = (float*)(Vt + (size_t)B_ * NH * SK_ * HD); // [B,SQ,DM] fp32

    // transient weight transposes, parked in regions not yet written:
    //   Wqt/Wkt/Wvt live in the ctx area (ctx is produced later by attn_mfma)
    //   Wot lives in the Qb area (Qb is dead after attn_mfma)
    __hip_bfloat16* Wqt = (__hip_bfloat16*)ctx;
    __hip_bfloat16* Wkt = Wqt + (size_t)DM * DM;
    __hip_bfloat16* Wvt = Wkt + (size_t)DM * DM;
    __hip_bfloat16* Wot = Qb;

    dim3 blk(256);
    hipLaunchKernelGGL(transpose_cast, dim3(12, 12, 3), blk, 0, stream,
                       Wq, Wk, Wv, Wqt, Wkt, Wvt);
    hipLaunchKernelGGL((gemm_mfma<0>), dim3((B_ * SQ_ / 128) * (DM / 128)), blk, 0, stream,
                       query, Wqt, (float*)nullptr, Qb, SQ_, (const float*)nullptr, (const float*)nullptr);
    hipLaunchKernelGGL((gemm_mfma<0>), dim3((B_ * SK_ / 128) * (DM / 128)), blk, 0, stream,
                       key, Wkt, (float*)nullptr, Kb, SK_, (const float*)nullptr, (const float*)nullptr);
    hipLaunchKernelGGL((gemm_mfma<2>), dim3((B_ * SK_ / 128) * (DM / 128)), blk, 0, stream,
                       value, Wvt, (float*)nullptr, Vt, SK_, (const float*)nullptr, (const float*)nullptr);
    hipLaunchKernelGGL(attn_mfma, dim3(B_ * NH * (SQ_ / QT)), blk, 0, stream,
                       Qb, Kb, Vt, mask, temp, attn, ctx);
    hipLaunchKernelGGL(transpose_cast, dim3(12, 12, 1), blk, 0, stream,
                       Wo, Wo, Wo, Wot, Wot, Wot);
    hipLaunchKernelGGL((gemm_mfma<1>), dim3((B_ * SQ_ / 128) * (DM / 128)), blk, 0, stream,
                       ctx, Wot, out, (__hip_bfloat16*)nullptr, SQ_, bo, query);
    hipLaunchKernelGGL(ln_kernel, dim3(B_ * SQ_), blk, 0, stream, out, gamma, beta);
}